// Round 20
// baseline (139.757 us; speedup 1.0000x reference)
//
#include <hip/hip_runtime.h>

// ---------------------------------------------------------------------------
// MultiHeadAttention forward, MI355X (gfx950), bf16 MFMA pipeline. Round 19:
//  - gemm_qkv reads fp32 inputs DIRECTLY (A staged as fp32 in LDS, converted
//    to bf16 at fragment read via cvt_pk) -> X bf16 round-trip eliminated
//    (~50 MB HBM). cvt_all now converts only the 4 weight matrices + mask.
//  - attn: R18 (perm-K, K=32 PV, MFMA-lr, XCD swizzle) - 46.2us measured.
//  - gemm_out: 128x64 dbuf.
// ---------------------------------------------------------------------------

typedef __attribute__((ext_vector_type(4))) float  f32x4;
typedef __attribute__((ext_vector_type(8))) __bf16 bf16x8;
typedef __attribute__((ext_vector_type(4))) __bf16 bf16x4;

#define SLEN 2048
#define BSZ  2
#define DMODEL 1024
#define NHEAD 16
#define DHEAD 64
#define D2 (2 * DMODEL)   // 2048 (Q|K buffer row)

__device__ __forceinline__ void async16(void* lds, const void* g) {
    __builtin_amdgcn_global_load_lds(
        (const __attribute__((address_space(1))) unsigned int*)g,
        (__attribute__((address_space(3))) unsigned int*)lds, 16, 0, 0);
}

__device__ __forceinline__ f32x4 mfma16(bf16x8 a, bf16x8 b, f32x4 c) {
    return __builtin_amdgcn_mfma_f32_16x16x32_bf16(a, b, c, 0, 0, 0);
}

// ------------------- convert weights fp32 -> bf16 (+ mask flag) ------------
struct CvtArgs {
    const float* src[4];
    __bf16* dst[4];
    int n4[4];
    float scale[4];
    const int* mask;
    unsigned int* flag;
    int maskn4;
};
__global__ void cvt_all(CvtArgs a) {
    const int t = blockIdx.y;
    const int stride = gridDim.x * blockDim.x;
    if (t == 4) {
        bool ok = true;
        for (int i = blockIdx.x * blockDim.x + threadIdx.x; i < a.maskn4; i += stride) {
            int4 v = ((const int4*)a.mask)[i];
            ok = ok && v.x && v.y && v.z && v.w;
        }
        if (!ok) atomicAnd(a.flag, 0u);
        return;
    }
    const float* __restrict__ src = a.src[t];
    __bf16* __restrict__ dst = a.dst[t];
    const int n4 = a.n4[t];
    const float sc = a.scale[t];
    for (int i = blockIdx.x * blockDim.x + threadIdx.x; i < n4; i += stride) {
        float4 v = ((const float4*)src)[i];
        bf16x4 o;
        o[0] = (__bf16)(v.x * sc); o[1] = (__bf16)(v.y * sc);
        o[2] = (__bf16)(v.z * sc); o[3] = (__bf16)(v.w * sc);
        ((bf16x4*)dst)[i] = o;
    }
}

// ------------------- gemm_qkv: 128x128xBK64, single-buf, fp32 A ------------
// A (query/keys/values) staged fp32 (32KB), converted at fragment read.
// bn 0..15 -> QK[4096][2048]; bn 16..23 -> V written in VT layout.
__global__ __launch_bounds__(256, 3) void gemm_qkv(const float* __restrict__ Xq,
                                                   const float* __restrict__ Xk,
                                                   const float* __restrict__ Xv,
                                                   const __bf16* __restrict__ W,
                                                   __bf16* __restrict__ QK,
                                                   __bf16* __restrict__ VT) {
    __shared__ float  Atf[128 * 64];    // 32 KB fp32 A tile
    __shared__ __bf16 Bt[128 * 64];     // 16 KB bf16 B tile
    const int tid = threadIdx.x;
    const int lane = tid & 63, wv = tid >> 6;
    const int l15 = lane & 15, l4 = lane >> 4;
    const int wr = wv >> 1, wc = wv & 1;
    const int srow = lane >> 3;
    const int sbyte = (((lane & 7) ^ srow) << 4);
    const int bm = blockIdx.x, bn = blockIdx.y;
    const float* A = (bn < 8) ? Xq : (bn < 16) ? Xk : Xv;
    const char* Ab = (const char*)(A + (size_t)bm * 128 * DMODEL);
    const char* Bb = (const char*)(W + (size_t)bn * 128 * DMODEL);

    f32x4 acc[4][4];
#pragma unroll
    for (int m = 0; m < 4; m++)
#pragma unroll
        for (int n = 0; n < 4; n++)
#pragma unroll
            for (int r = 0; r < 4; r++) acc[m][n][r] = 0.0f;

    for (int k0 = 0; k0 < DMODEL; k0 += 64) {
        __syncthreads();
        // stage: A = 32 fp32 chunks (4 rows x 256B each), B = 16 bf16 chunks
#pragma unroll
        for (int i = 0; i < 12; i++) {
            int c = wv * 12 + i;      // 0..47
            if (c < 32) {
                int row = c * 4 + (lane >> 4);
                int sb = ((lane & 15) << 4) ^ ((row & 7) << 4);
                async16(&Atf[c * 256], Ab + (size_t)row * (DMODEL * 4) + k0 * 4 + sb);
            } else {
                int c2 = c - 32;
                int row = c2 * 8 + srow;
                async16(&Bt[c2 * 512], Bb + ((size_t)row * DMODEL + k0) * 2 + sbyte);
            }
        }
        __syncthreads();

#pragma unroll
        for (int kk = 0; kk < 2; kk++) {
            bf16x8 af[4], bfr[4];
#pragma unroll
            for (int m = 0; m < 4; m++) {
                int row = wr * 64 + m * 16 + l15;
                int basef = kk * 32 + l4 * 8;
                f32x4 lo = *(const f32x4*)&Atf[row * 64 + (basef ^ ((row & 7) << 2))];
                f32x4 hi = *(const f32x4*)&Atf[row * 64 + ((basef + 4) ^ ((row & 7) << 2))];
#pragma unroll
                for (int j = 0; j < 4; j++) {
                    af[m][j]     = (__bf16)lo[j];
                    af[m][4 + j] = (__bf16)hi[j];
                }
            }
#pragma unroll
            for (int n = 0; n < 4; n++) {
                int row = wc * 64 + n * 16 + l15;
                int col = (kk * 32 + l4 * 8) ^ ((row & 7) << 3);
                bfr[n] = *(const bf16x8*)&Bt[row * 64 + col];
            }
#pragma unroll
            for (int m = 0; m < 4; m++)
#pragma unroll
                for (int n = 0; n < 4; n++)
                    acc[m][n] = mfma16(af[m], bfr[n], acc[m][n]);
        }
    }

    if (bn < 16) {
#pragma unroll
        for (int m = 0; m < 4; m++)
#pragma unroll
            for (int n = 0; n < 4; n++)
#pragma unroll
                for (int r = 0; r < 4; r++) {
                    size_t row = (size_t)bm * 128 + wr * 64 + m * 16 + l4 * 4 + r;
                    size_t col = (size_t)bn * 128 + wc * 64 + n * 16 + l15;
                    QK[row * D2 + col] = (__bf16)acc[m][n][r];
                }
    } else {
        // V -> VT[((b*16+h)*64 + d)*2048 + s]; t=row: s=t>>1, b=t&1
#pragma unroll
        for (int m = 0; m < 4; m++)
#pragma unroll
            for (int n = 0; n < 4; n++)
#pragma unroll
                for (int r = 0; r < 4; r++) {
                    int t = bm * 128 + wr * 64 + m * 16 + l4 * 4 + r;
                    int hd = (bn - 16) * 128 + wc * 64 + n * 16 + l15;
                    int s = t >> 1, b = t & 1;
                    VT[((size_t)(b * NHEAD * DHEAD + hd)) * SLEN + s] = (__bf16)acc[m][n][r];
                }
    }
}

// ---------------------------- gemm_out: 128x64x64 dbuf ---------------------
__global__ __launch_bounds__(256, 2) void gemm_out(const __bf16* __restrict__ A,
                                                   const __bf16* __restrict__ B,
                                                   float* __restrict__ Cv) {
    __shared__ __bf16 At[2][128 * 64];
    __shared__ __bf16 Bt[2][64 * 64];
    const int tid = threadIdx.x;
    const int lane = tid & 63, wv = tid >> 6;
    const int l15 = lane & 15, l4 = lane >> 4;
    const int wr = wv >> 1, wc = wv & 1;
    const int srow = lane >> 3;
    const int sbyte = (((lane & 7) ^ srow) << 4);
    const int bm = blockIdx.x, bn = blockIdx.y;
    const char* Ab = (const char*)(A + (size_t)bm * 128 * DMODEL);
    const char* Bb = (const char*)(B + (size_t)bn * 64 * DMODEL);

    f32x4 acc[4][2];
#pragma unroll
    for (int m = 0; m < 4; m++)
#pragma unroll
        for (int n = 0; n < 2; n++)
#pragma unroll
            for (int r = 0; r < 4; r++) acc[m][n][r] = 0.0f;

    auto stage = [&](int buf, int k0) {
#pragma unroll
        for (int i = 0; i < 6; i++) {
            int c = wv * 6 + i;
            if (c < 16) {
                int row = c * 8 + srow;
                async16(&At[buf][c * 512], Ab + ((size_t)row * DMODEL + k0) * 2 + sbyte);
            } else {
                int row = (c - 16) * 8 + srow;
                async16(&Bt[buf][(c - 16) * 512], Bb + ((size_t)row * DMODEL + k0) * 2 + sbyte);
            }
        }
    };

    stage(0, 0);
    __syncthreads();
    int cur = 0;
    for (int k0 = 0; k0 < DMODEL; k0 += 64) {
        if (k0 + 64 < DMODEL) stage(cur ^ 1, k0 + 64);
#pragma unroll
        for (int kk = 0; kk < 2; kk++) {
            bf16x8 af[4], bfr[2];
#pragma unroll
            for (int m = 0; m < 4; m++) {
                int row = wr * 64 + m * 16 + l15;
                int col = (kk * 32 + l4 * 8) ^ ((row & 7) << 3);
                af[m] = *(const bf16x8*)&At[cur][row * 64 + col];
            }
#pragma unroll
            for (int n = 0; n < 2; n++) {
                int row = wc * 32 + n * 16 + l15;
                int col = (kk * 32 + l4 * 8) ^ ((row & 7) << 3);
                bfr[n] = *(const bf16x8*)&Bt[cur][row * 64 + col];
            }
#pragma unroll
            for (int m = 0; m < 4; m++)
#pragma unroll
                for (int n = 0; n < 2; n++)
                    acc[m][n] = mfma16(af[m], bfr[n], acc[m][n]);
        }
        __syncthreads();
        cur ^= 1;
    }

#pragma unroll
    for (int m = 0; m < 4; m++)
#pragma unroll
        for (int n = 0; n < 2; n++)
#pragma unroll
            for (int r = 0; r < 4; r++) {
                size_t row = (size_t)bm * 128 + wr * 64 + m * 16 + l4 * 4 + r;
                size_t col = (size_t)bn * 64 + wc * 32 + n * 16 + l15;
                Cv[row * DMODEL + col] = acc[m][n][r];
            }
}

// ---------------------------- attention (perm-K, K=32 PV, MFMA-lr) ---------
__global__ __launch_bounds__(256, 2) void attn_fwd(const __bf16* __restrict__ QK,
                                                   const __bf16* __restrict__ Vt,
                                                   const int* __restrict__ mask,
                                                   const unsigned int* __restrict__ flag,
                                                   __bf16* __restrict__ Attn) {
    __shared__ __bf16 Kt[2][2][64 * 64];
    __shared__ __bf16 Vs[2][2][64 * 64];
    const int tid = threadIdx.x;
    const int lane = tid & 63, wv = tid >> 6;
    const int l15 = lane & 15, l4 = lane >> 4;
    const int blk = blockIdx.x;
    const int xcd = blk & 7, idx = blk >> 3;
    const int bh = xcd + (idx >> 4) * 8;
    const int qt = idx & 15;
    const int b = bh >> 4, h = bh & 15;
    const bool allones = (*flag != 0u);
    const int srow = lane >> 3;
    const int sbyte = (((lane & 7) ^ srow) << 4);

    bf16x8 aq[2][2];
#pragma unroll
    for (int m = 0; m < 2; m++)
#pragma unroll
        for (int kk = 0; kk < 2; kk++) {
            int qrow = qt * 128 + wv * 32 + m * 16 + l15;
            aq[m][kk] = *(const bf16x8*)(QK + ((size_t)(qrow * BSZ + b) * D2 + h * 64 + kk * 32 + l4 * 8));
        }

    bf16x8 ones;
#pragma unroll
    for (int j = 0; j < 8; j++) ones[j] = (__bf16)1.0f;

    f32x4 o[2][4], olr[2];
#pragma unroll
    for (int m = 0; m < 2; m++) {
#pragma unroll
        for (int nd = 0; nd < 4; nd++)
#pragma unroll
            for (int r = 0; r < 4; r++) o[m][nd][r] = 0.0f;
#pragma unroll
        for (int r = 0; r < 4; r++) olr[m][r] = 0.0f;
    }

    const char* Kb = (const char*)QK + ((size_t)b * D2 + DMODEL + h * 64) * 2;
    const char* Vb = (const char*)Vt + ((size_t)bh * 64) * SLEN * 2;

    auto stage = [&](int buf, int kt) {
#pragma unroll
        for (int i = 0; i < 8; i++) {
            int c = wv * 8 + i;
            if (c < 16) {
                int kh = c >> 3, ck = c & 7;
                int p = (ck & 7) * 8 + srow;
                int kperm = (p & 32) + ((p & 12) << 1) + (((p >> 4) & 1) << 2) + (p & 3);
                int krow = kt * 128 + kh * 64 + kperm;
                async16(&Kt[buf][kh][ck * 512],
                        Kb + (size_t)krow * (BSZ * D2 * 2) + sbyte);
            } else {
                int c2 = c - 16;
                int kh = c2 >> 3, ck = c2 & 7;
                int drow = ck * 8 + srow;
                async16(&Vs[buf][kh][ck * 512],
                        Vb + (size_t)drow * (SLEN * 2) + kt * 256 + kh * 128 + sbyte);
            }
        }
    };

    stage(0, 0);
    __syncthreads();
    int cur = 0;

    for (int kt = 0; kt < SLEN / 128; kt++) {
        if (kt + 1 < SLEN / 128) stage(cur ^ 1, kt + 1);

#pragma unroll
        for (int kh = 0; kh < 2; kh++) {
            const __bf16* Kl = Kt[cur][kh];
            const __bf16* Vl = Vs[cur][kh];

            bf16x8 bk[4][2];
#pragma unroll
            for (int n = 0; n < 4; n++) {
                int row = n * 16 + l15;
#pragma unroll
                for (int kk = 0; kk < 2; kk++) {
                    int col = (kk * 32 + l4 * 8) ^ ((row & 7) << 3);
                    bk[n][kk] = *(const bf16x8*)&Kl[row * 64 + col];
                }
            }

            f32x4 s[2][4];
#pragma unroll
            for (int m = 0; m < 2; m++)
#pragma unroll
                for (int n = 0; n < 4; n++)
#pragma unroll
                    for (int r = 0; r < 4; r++) s[m][n][r] = 0.0f;
            __builtin_amdgcn_s_setprio(1);
#pragma unroll
            for (int n = 0; n < 4; n++)
#pragma unroll
                for (int kk = 0; kk < 2; kk++)
#pragma unroll
                    for (int m = 0; m < 2; m++)
                        s[m][n] = mfma16(bk[n][kk], aq[m][kk], s[m][n]);
            __builtin_amdgcn_s_setprio(0);

            if (!allones) {
#pragma unroll
                for (int m = 0; m < 2; m++) {
                    int q = qt * 128 + wv * 32 + m * 16 + l15;
#pragma unroll
                    for (int n = 0; n < 4; n++)
#pragma unroll
                        for (int r = 0; r < 4; r++) {
                            int kg = kt * 128 + kh * 64 + (n >> 1) * 32 + l4 * 8 + (n & 1) * 4 + r;
                            if (mask[(size_t)q * SLEN + kg] == 0) s[m][n][r] = -1e20f;
                        }
                }
            }

            bf16x8 pb8[2][2];
#pragma unroll
            for (int m = 0; m < 2; m++)
#pragma unroll
                for (int half = 0; half < 2; half++)
#pragma unroll
                    for (int nn = 0; nn < 2; nn++)
#pragma unroll
                        for (int r = 0; r < 4; r++) {
                            float p = __builtin_amdgcn_exp2f(s[m][half * 2 + nn][r]);
                            pb8[m][half][nn * 4 + r] = (__bf16)p;
                        }

            __builtin_amdgcn_s_setprio(1);
#pragma unroll
            for (int half = 0; half < 2; half++) {
#pragma unroll
                for (int nd = 0; nd < 4; nd++) {
                    int row = nd * 16 + l15;
                    int col = (half * 32 + l4 * 8) ^ ((row & 7) << 3);
                    bf16x8 av = *(const bf16x8*)&Vl[row * 64 + col];
#pragma unroll
                    for (int m = 0; m < 2; m++)
                        o[m][nd] = mfma16(av, pb8[m][half], o[m][nd]);
                }
#pragma unroll
                for (int m = 0; m < 2; m++)
                    olr[m] = mfma16(ones, pb8[m][half], olr[m]);
            }
            __builtin_amdgcn_s_setprio(0);
        }

        __syncthreads();
        cur ^= 1;
    }

#pragma unroll
    for (int m = 0; m < 2; m++) {
        float inv = 1.0f / olr[m][0];
        int qrow = qt * 128 + wv * 32 + m * 16 + l15;
#pragma unroll
        for (int nd = 0; nd < 4; nd++) {
            bf16x4 ov;
#pragma unroll
            for (int r = 0; r < 4; r++) ov[r] = (__bf16)(o[m][nd][r] * inv);
            *(bf16x4*)(Attn + ((size_t)(qrow * BSZ + b)) * DMODEL + h * 64 + nd * 16 + l4 * 4) = ov;
        }
    }
}

// ---------------------------- launcher -------------------------------------
extern "C" void kernel_launch(void* const* d_in, const int* in_sizes, int n_in,
                              void* d_out, int out_size, void* d_ws, size_t ws_size,
                              hipStream_t stream) {
    const float* query  = (const float*)d_in[0];
    const float* keys   = (const float*)d_in[1];
    const float* values = (const float*)d_in[2];
    const int*   mask   = (const int*)d_in[3];
    const float* Wq     = (const float*)d_in[4];
    const float* Wk     = (const float*)d_in[5];
    const float* Wv     = (const float*)d_in[6];
    const float* Wo     = (const float*)d_in[7];
    float* out = (float*)d_out;

    char* ws = (char*)d_ws;
    const size_t MB = 1024 * 1024;
    __bf16* WCAT = (__bf16*)(ws + 0);         // [3072][1024] Wq|Wk|Wv = 6 MB
    __bf16* WQB  = WCAT;
    __bf16* WKB  = (__bf16*)(ws + 2 * MB);
    __bf16* WVB  = (__bf16*)(ws + 4 * MB);
    __bf16* WOB  = (__bf16*)(ws + 6 * MB);    // 2 MB
    __bf16* QKB  = (__bf16*)(ws + 8 * MB);    // [4096][2048] Q|K = 16 MB
    __bf16* VT   = (__bf16*)(ws + 24 * MB);   // V^T = 8 MB
    __bf16* ATT  = (__bf16*)(ws + 33 * MB);   // 8 MB
    unsigned int* flag = (unsigned int*)(ws + 42 * MB);

    (void)hipMemsetAsync(flag, 0xFF, 4, stream);

    const int NTOK = SLEN * BSZ;  // 4096
    const int NW = DMODEL * DMODEL / 4;
    const float LOG2E = 1.4426950408889634f;
    CvtArgs ca;
    ca.src[0] = Wq; ca.dst[0] = WQB; ca.n4[0] = NW; ca.scale[0] = LOG2E;
    ca.src[1] = Wk; ca.dst[1] = WKB; ca.n4[1] = NW; ca.scale[1] = 1.0f;
    ca.src[2] = Wv; ca.dst[2] = WVB; ca.n4[2] = NW; ca.scale[2] = 1.0f;
    ca.src[3] = Wo; ca.dst[3] = WOB; ca.n4[3] = NW; ca.scale[3] = 1.0f;
    ca.mask = mask; ca.flag = flag; ca.maskn4 = SLEN * SLEN / 4;
    cvt_all<<<dim3(256, 5), 256, 0, stream>>>(ca);

    // fused QKV projection (fp32 A) + V-transpose: grid (32, 24)
    gemm_qkv<<<dim3(NTOK / 128, 3 * DMODEL / 128), 256, 0, stream>>>(query, keys, values, WCAT, QKB, VT);

    attn_fwd<<<BSZ * NHEAD * (SLEN / 128), 256, 0, stream>>>(QKB, VT, mask, flag, ATT);

    gemm_out<<<dim3(NTOK / 128, DMODEL / 64), 256, 0, stream>>>(ATT, WOB, out);
}

// Round 22
// 119.037 us; speedup vs baseline: 1.1741x; 1.1741x over previous
//
#include <hip/hip_runtime.h>

// ---------------------------------------------------------------------------
// MultiHeadAttention forward, MI355X (gfx950), bf16 MFMA pipeline. Round 21:
// REVERT to R18 (118.8us best). R19/R20's fp32-A-direct gemm_qkv regressed
// 29->109us (fp32 staging doubled LDS drain volume + L2/L3 traffic).
//  - cvt_all: fp32->bf16 for X inputs + weights, + mask flag (one dispatch).
//  - gemm_qkv: 128^2xBK64 single-buf; V written directly in VT layout.
//  - attn: perm-K staging, K=32 PV, in-register P, MFMA-lr, XCD swizzle.
//  - gemm_out: 128x64x64 dbuf.
// ---------------------------------------------------------------------------

typedef __attribute__((ext_vector_type(4))) float  f32x4;
typedef __attribute__((ext_vector_type(8))) __bf16 bf16x8;
typedef __attribute__((ext_vector_type(4))) __bf16 bf16x4;

#define SLEN 2048
#define BSZ  2
#define DMODEL 1024
#define NHEAD 16
#define DHEAD 64
#define D2 (2 * DMODEL)   // 2048 (Q|K buffer row)

__device__ __forceinline__ void async16(void* lds, const void* g) {
    __builtin_amdgcn_global_load_lds(
        (const __attribute__((address_space(1))) unsigned int*)g,
        (__attribute__((address_space(3))) unsigned int*)lds, 16, 0, 0);
}

__device__ __forceinline__ f32x4 mfma16(bf16x8 a, bf16x8 b, f32x4 c) {
    return __builtin_amdgcn_mfma_f32_16x16x32_bf16(a, b, c, 0, 0, 0);
}

// ------------------- fused convert fp32 -> bf16 (+ mask flag) --------------
struct CvtArgs {
    const float* src[7];
    __bf16* dst[7];
    int n4[7];
    float scale[7];
    const int* mask;
    unsigned int* flag;
    int maskn4;
};
__global__ void cvt_all(CvtArgs a) {
    const int t = blockIdx.y;
    const int stride = gridDim.x * blockDim.x;
    if (t == 7) {
        bool ok = true;
        for (int i = blockIdx.x * blockDim.x + threadIdx.x; i < a.maskn4; i += stride) {
            int4 v = ((const int4*)a.mask)[i];
            ok = ok && v.x && v.y && v.z && v.w;
        }
        if (!ok) atomicAnd(a.flag, 0u);
        return;
    }
    const float* __restrict__ src = a.src[t];
    __bf16* __restrict__ dst = a.dst[t];
    const int n4 = a.n4[t];
    const float sc = a.scale[t];
    for (int i = blockIdx.x * blockDim.x + threadIdx.x; i < n4; i += stride) {
        float4 v = ((const float4*)src)[i];
        bf16x4 o;
        o[0] = (__bf16)(v.x * sc); o[1] = (__bf16)(v.y * sc);
        o[2] = (__bf16)(v.z * sc); o[3] = (__bf16)(v.w * sc);
        ((bf16x4*)dst)[i] = o;
    }
}

// ------------------- gemm_qkv: 128x128xBK64, single-buf m97 loop -----------
// bn 0..15 -> QK[4096][2048]; bn 16..23 -> V written in VT layout.
__global__ __launch_bounds__(256, 3) void gemm_qkv(const __bf16* __restrict__ Xq,
                                                   const __bf16* __restrict__ Xk,
                                                   const __bf16* __restrict__ Xv,
                                                   const __bf16* __restrict__ W,
                                                   __bf16* __restrict__ QK,
                                                   __bf16* __restrict__ VT) {
    __shared__ __bf16 At[128 * 64];
    __shared__ __bf16 Bt[128 * 64];
    const int tid = threadIdx.x;
    const int lane = tid & 63, wv = tid >> 6;
    const int l15 = lane & 15, l4 = lane >> 4;
    const int wr = wv >> 1, wc = wv & 1;
    const int srow = lane >> 3;
    const int sbyte = (((lane & 7) ^ srow) << 4);
    const int bm = blockIdx.x, bn = blockIdx.y;
    const __bf16* A = (bn < 8) ? Xq : (bn < 16) ? Xk : Xv;
    const char* Ab = (const char*)(A + (size_t)bm * 128 * DMODEL);
    const char* Bb = (const char*)(W + (size_t)bn * 128 * DMODEL);

    f32x4 acc[4][4];
#pragma unroll
    for (int m = 0; m < 4; m++)
#pragma unroll
        for (int n = 0; n < 4; n++)
#pragma unroll
            for (int r = 0; r < 4; r++) acc[m][n][r] = 0.0f;

    for (int k0 = 0; k0 < DMODEL; k0 += 64) {
        __syncthreads();
#pragma unroll
        for (int i = 0; i < 8; i++) {
            int c = wv * 8 + i;
            if (c < 16) {
                int row = c * 8 + srow;
                async16(&At[c * 512], Ab + ((size_t)row * DMODEL + k0) * 2 + sbyte);
            } else {
                int row = (c - 16) * 8 + srow;
                async16(&Bt[(c - 16) * 512], Bb + ((size_t)row * DMODEL + k0) * 2 + sbyte);
            }
        }
        __syncthreads();

#pragma unroll
        for (int kk = 0; kk < 2; kk++) {
            bf16x8 af[4], bfr[4];
#pragma unroll
            for (int m = 0; m < 4; m++) {
                int row = wr * 64 + m * 16 + l15;
                int col = (kk * 32 + l4 * 8) ^ ((row & 7) << 3);
                af[m] = *(const bf16x8*)&At[row * 64 + col];
            }
#pragma unroll
            for (int n = 0; n < 4; n++) {
                int row = wc * 64 + n * 16 + l15;
                int col = (kk * 32 + l4 * 8) ^ ((row & 7) << 3);
                bfr[n] = *(const bf16x8*)&Bt[row * 64 + col];
            }
#pragma unroll
            for (int m = 0; m < 4; m++)
#pragma unroll
                for (int n = 0; n < 4; n++)
                    acc[m][n] = mfma16(af[m], bfr[n], acc[m][n]);
        }
    }

    if (bn < 16) {
#pragma unroll
        for (int m = 0; m < 4; m++)
#pragma unroll
            for (int n = 0; n < 4; n++)
#pragma unroll
                for (int r = 0; r < 4; r++) {
                    size_t row = (size_t)bm * 128 + wr * 64 + m * 16 + l4 * 4 + r;
                    size_t col = (size_t)bn * 128 + wc * 64 + n * 16 + l15;
                    QK[row * D2 + col] = (__bf16)acc[m][n][r];
                }
    } else {
        // V -> VT[((b*16+h)*64 + d)*2048 + s]; t=row: s=t>>1, b=t&1
#pragma unroll
        for (int m = 0; m < 4; m++)
#pragma unroll
            for (int n = 0; n < 4; n++)
#pragma unroll
                for (int r = 0; r < 4; r++) {
                    int t = bm * 128 + wr * 64 + m * 16 + l4 * 4 + r;
                    int hd = (bn - 16) * 128 + wc * 64 + n * 16 + l15;
                    int s = t >> 1, b = t & 1;
                    VT[((size_t)(b * NHEAD * DHEAD + hd)) * SLEN + s] = (__bf16)acc[m][n][r];
                }
    }
}

// ---------------------------- gemm_out: 128x64x64 dbuf ---------------------
__global__ __launch_bounds__(256, 2) void gemm_out(const __bf16* __restrict__ A,
                                                   const __bf16* __restrict__ B,
                                                   float* __restrict__ Cv) {
    __shared__ __bf16 At[2][128 * 64];
    __shared__ __bf16 Bt[2][64 * 64];
    const int tid = threadIdx.x;
    const int lane = tid & 63, wv = tid >> 6;
    const int l15 = lane & 15, l4 = lane >> 4;
    const int wr = wv >> 1, wc = wv & 1;
    const int srow = lane >> 3;
    const int sbyte = (((lane & 7) ^ srow) << 4);
    const int bm = blockIdx.x, bn = blockIdx.y;
    const char* Ab = (const char*)(A + (size_t)bm * 128 * DMODEL);
    const char* Bb = (const char*)(B + (size_t)bn * 64 * DMODEL);

    f32x4 acc[4][2];
#pragma unroll
    for (int m = 0; m < 4; m++)
#pragma unroll
        for (int n = 0; n < 2; n++)
#pragma unroll
            for (int r = 0; r < 4; r++) acc[m][n][r] = 0.0f;

    auto stage = [&](int buf, int k0) {
#pragma unroll
        for (int i = 0; i < 6; i++) {
            int c = wv * 6 + i;
            if (c < 16) {
                int row = c * 8 + srow;
                async16(&At[buf][c * 512], Ab + ((size_t)row * DMODEL + k0) * 2 + sbyte);
            } else {
                int row = (c - 16) * 8 + srow;
                async16(&Bt[buf][(c - 16) * 512], Bb + ((size_t)row * DMODEL + k0) * 2 + sbyte);
            }
        }
    };

    stage(0, 0);
    __syncthreads();
    int cur = 0;
    for (int k0 = 0; k0 < DMODEL; k0 += 64) {
        if (k0 + 64 < DMODEL) stage(cur ^ 1, k0 + 64);
#pragma unroll
        for (int kk = 0; kk < 2; kk++) {
            bf16x8 af[4], bfr[2];
#pragma unroll
            for (int m = 0; m < 4; m++) {
                int row = wr * 64 + m * 16 + l15;
                int col = (kk * 32 + l4 * 8) ^ ((row & 7) << 3);
                af[m] = *(const bf16x8*)&At[cur][row * 64 + col];
            }
#pragma unroll
            for (int n = 0; n < 2; n++) {
                int row = wc * 32 + n * 16 + l15;
                int col = (kk * 32 + l4 * 8) ^ ((row & 7) << 3);
                bfr[n] = *(const bf16x8*)&Bt[cur][row * 64 + col];
            }
#pragma unroll
            for (int m = 0; m < 4; m++)
#pragma unroll
                for (int n = 0; n < 2; n++)
                    acc[m][n] = mfma16(af[m], bfr[n], acc[m][n]);
        }
        __syncthreads();
        cur ^= 1;
    }

#pragma unroll
    for (int m = 0; m < 4; m++)
#pragma unroll
        for (int n = 0; n < 2; n++)
#pragma unroll
            for (int r = 0; r < 4; r++) {
                size_t row = (size_t)bm * 128 + wr * 64 + m * 16 + l4 * 4 + r;
                size_t col = (size_t)bn * 64 + wc * 32 + n * 16 + l15;
                Cv[row * DMODEL + col] = acc[m][n][r];
            }
}

// ---------------------------- attention (perm-K, K=32 PV, MFMA-lr) ---------
__global__ __launch_bounds__(256, 2) void attn_fwd(const __bf16* __restrict__ QK,
                                                   const __bf16* __restrict__ Vt,
                                                   const int* __restrict__ mask,
                                                   const unsigned int* __restrict__ flag,
                                                   __bf16* __restrict__ Attn) {
    __shared__ __bf16 Kt[2][2][64 * 64];
    __shared__ __bf16 Vs[2][2][64 * 64];
    const int tid = threadIdx.x;
    const int lane = tid & 63, wv = tid >> 6;
    const int l15 = lane & 15, l4 = lane >> 4;
    const int blk = blockIdx.x;
    const int xcd = blk & 7, idx = blk >> 3;
    const int bh = xcd + (idx >> 4) * 8;
    const int qt = idx & 15;
    const int b = bh >> 4, h = bh & 15;
    const bool allones = (*flag != 0u);
    const int srow = lane >> 3;
    const int sbyte = (((lane & 7) ^ srow) << 4);

    bf16x8 aq[2][2];
#pragma unroll
    for (int m = 0; m < 2; m++)
#pragma unroll
        for (int kk = 0; kk < 2; kk++) {
            int qrow = qt * 128 + wv * 32 + m * 16 + l15;
            aq[m][kk] = *(const bf16x8*)(QK + ((size_t)(qrow * BSZ + b) * D2 + h * 64 + kk * 32 + l4 * 8));
        }

    bf16x8 ones;
#pragma unroll
    for (int j = 0; j < 8; j++) ones[j] = (__bf16)1.0f;

    f32x4 o[2][4], olr[2];
#pragma unroll
    for (int m = 0; m < 2; m++) {
#pragma unroll
        for (int nd = 0; nd < 4; nd++)
#pragma unroll
            for (int r = 0; r < 4; r++) o[m][nd][r] = 0.0f;
#pragma unroll
        for (int r = 0; r < 4; r++) olr[m][r] = 0.0f;
    }

    const char* Kb = (const char*)QK + ((size_t)b * D2 + DMODEL + h * 64) * 2;
    const char* Vb = (const char*)Vt + ((size_t)bh * 64) * SLEN * 2;

    auto stage = [&](int buf, int kt) {
#pragma unroll
        for (int i = 0; i < 8; i++) {
            int c = wv * 8 + i;
            if (c < 16) {
                int kh = c >> 3, ck = c & 7;
                int p = (ck & 7) * 8 + srow;
                int kperm = (p & 32) + ((p & 12) << 1) + (((p >> 4) & 1) << 2) + (p & 3);
                int krow = kt * 128 + kh * 64 + kperm;
                async16(&Kt[buf][kh][ck * 512],
                        Kb + (size_t)krow * (BSZ * D2 * 2) + sbyte);
            } else {
                int c2 = c - 16;
                int kh = c2 >> 3, ck = c2 & 7;
                int drow = ck * 8 + srow;
                async16(&Vs[buf][kh][ck * 512],
                        Vb + (size_t)drow * (SLEN * 2) + kt * 256 + kh * 128 + sbyte);
            }
        }
    };

    stage(0, 0);
    __syncthreads();
    int cur = 0;

    for (int kt = 0; kt < SLEN / 128; kt++) {
        if (kt + 1 < SLEN / 128) stage(cur ^ 1, kt + 1);

#pragma unroll
        for (int kh = 0; kh < 2; kh++) {
            const __bf16* Kl = Kt[cur][kh];
            const __bf16* Vl = Vs[cur][kh];

            bf16x8 bk[4][2];
#pragma unroll
            for (int n = 0; n < 4; n++) {
                int row = n * 16 + l15;
#pragma unroll
                for (int kk = 0; kk < 2; kk++) {
                    int col = (kk * 32 + l4 * 8) ^ ((row & 7) << 3);
                    bk[n][kk] = *(const bf16x8*)&Kl[row * 64 + col];
                }
            }

            f32x4 s[2][4];
#pragma unroll
            for (int m = 0; m < 2; m++)
#pragma unroll
                for (int n = 0; n < 4; n++)
#pragma unroll
                    for (int r = 0; r < 4; r++) s[m][n][r] = 0.0f;
            __builtin_amdgcn_s_setprio(1);
#pragma unroll
            for (int n = 0; n < 4; n++)
#pragma unroll
                for (int kk = 0; kk < 2; kk++)
#pragma unroll
                    for (int m = 0; m < 2; m++)
                        s[m][n] = mfma16(bk[n][kk], aq[m][kk], s[m][n]);
            __builtin_amdgcn_s_setprio(0);

            if (!allones) {
#pragma unroll
                for (int m = 0; m < 2; m++) {
                    int q = qt * 128 + wv * 32 + m * 16 + l15;
#pragma unroll
                    for (int n = 0; n < 4; n++)
#pragma unroll
                        for (int r = 0; r < 4; r++) {
                            int kg = kt * 128 + kh * 64 + (n >> 1) * 32 + l4 * 8 + (n & 1) * 4 + r;
                            if (mask[(size_t)q * SLEN + kg] == 0) s[m][n][r] = -1e20f;
                        }
                }
            }

            bf16x8 pb8[2][2];
#pragma unroll
            for (int m = 0; m < 2; m++)
#pragma unroll
                for (int half = 0; half < 2; half++)
#pragma unroll
                    for (int nn = 0; nn < 2; nn++)
#pragma unroll
                        for (int r = 0; r < 4; r++) {
                            float p = __builtin_amdgcn_exp2f(s[m][half * 2 + nn][r]);
                            pb8[m][half][nn * 4 + r] = (__bf16)p;
                        }

            __builtin_amdgcn_s_setprio(1);
#pragma unroll
            for (int half = 0; half < 2; half++) {
#pragma unroll
                for (int nd = 0; nd < 4; nd++) {
                    int row = nd * 16 + l15;
                    int col = (half * 32 + l4 * 8) ^ ((row & 7) << 3);
                    bf16x8 av = *(const bf16x8*)&Vl[row * 64 + col];
#pragma unroll
                    for (int m = 0; m < 2; m++)
                        o[m][nd] = mfma16(av, pb8[m][half], o[m][nd]);
                }
#pragma unroll
                for (int m = 0; m < 2; m++)
                    olr[m] = mfma16(ones, pb8[m][half], olr[m]);
            }
            __builtin_amdgcn_s_setprio(0);
        }

        __syncthreads();
        cur ^= 1;
    }

#pragma unroll
    for (int m = 0; m < 2; m++) {
        float inv = 1.0f / olr[m][0];
        int qrow = qt * 128 + wv * 32 + m * 16 + l15;
#pragma unroll
        for (int nd = 0; nd < 4; nd++) {
            bf16x4 ov;
#pragma unroll
            for (int r = 0; r < 4; r++) ov[r] = (__bf16)(o[m][nd][r] * inv);
            *(bf16x4*)(Attn + ((size_t)(qrow * BSZ + b)) * DMODEL + h * 64 + nd * 16 + l4 * 4) = ov;
        }
    }
}

// ---------------------------- launcher -------------------------------------
extern "C" void kernel_launch(void* const* d_in, const int* in_sizes, int n_in,
                              void* d_out, int out_size, void* d_ws, size_t ws_size,
                              hipStream_t stream) {
    const float* query  = (const float*)d_in[0];
    const float* keys   = (const float*)d_in[1];
    const float* values = (const float*)d_in[2];
    const int*   mask   = (const int*)d_in[3];
    const float* Wq     = (const float*)d_in[4];
    const float* Wk     = (const float*)d_in[5];
    const float* Wv     = (const float*)d_in[6];
    const float* Wo     = (const float*)d_in[7];
    float* out = (float*)d_out;

    char* ws = (char*)d_ws;
    const size_t MB = 1024 * 1024;
    __bf16* XQ   = (__bf16*)(ws + 0);
    __bf16* XK   = (__bf16*)(ws + 8 * MB);
    __bf16* XV   = (__bf16*)(ws + 16 * MB);
    __bf16* WCAT = (__bf16*)(ws + 24 * MB);   // [3072][1024]: Wq|Wk|Wv
    __bf16* WQB  = WCAT;
    __bf16* WKB  = (__bf16*)(ws + 26 * MB);
    __bf16* WVB  = (__bf16*)(ws + 28 * MB);
    __bf16* WOB  = (__bf16*)(ws + 30 * MB);
    __bf16* QKB  = (__bf16*)(ws + 32 * MB);   // [4096][2048] Q|K = 16 MB
    __bf16* VT   = (__bf16*)(ws + 48 * MB);   // V^T = 8 MB
    __bf16* ATT  = (__bf16*)(ws + 8 * MB);    // reuse XK (free after gemm_qkv)
    unsigned int* flag = (unsigned int*)(ws + 56 * MB);

    (void)hipMemsetAsync(flag, 0xFF, 4, stream);

    const int NTOK = SLEN * BSZ;  // 4096
    const int NBIG = NTOK * DMODEL / 4, NW = DMODEL * DMODEL / 4;
    const float LOG2E = 1.4426950408889634f;
    CvtArgs ca;
    ca.src[0] = query;  ca.dst[0] = XQ;  ca.n4[0] = NBIG; ca.scale[0] = 1.0f;
    ca.src[1] = keys;   ca.dst[1] = XK;  ca.n4[1] = NBIG; ca.scale[1] = 1.0f;
    ca.src[2] = values; ca.dst[2] = XV;  ca.n4[2] = NBIG; ca.scale[2] = 1.0f;
    ca.src[3] = Wq;     ca.dst[3] = WQB; ca.n4[3] = NW;   ca.scale[3] = LOG2E;
    ca.src[4] = Wk;     ca.dst[4] = WKB; ca.n4[4] = NW;   ca.scale[4] = 1.0f;
    ca.src[5] = Wv;     ca.dst[5] = WVB; ca.n4[5] = NW;   ca.scale[5] = 1.0f;
    ca.src[6] = Wo;     ca.dst[6] = WOB; ca.n4[6] = NW;   ca.scale[6] = 1.0f;
    ca.mask = mask; ca.flag = flag; ca.maskn4 = SLEN * SLEN / 4;
    cvt_all<<<dim3(256, 8), 256, 0, stream>>>(ca);

    // fused QKV projection + V-transpose: grid (32, 24)
    gemm_qkv<<<dim3(NTOK / 128, 3 * DMODEL / 128), 256, 0, stream>>>(XQ, XK, XV, WCAT, QKB, VT);

    attn_fwd<<<BSZ * NHEAD * (SLEN / 128), 256, 0, stream>>>(QKB, VT, mask, flag, ATT);

    gemm_out<<<dim3(NTOK / 128, DMODEL / 64), 256, 0, stream>>>(ATT, WOB, out);
}